// Round 10
// baseline (666.606 us; speedup 1.0000x reference)
//
#include <hip/hip_runtime.h>
#include <math.h>

#define DDIM 256
#define NSPLIT 2
#define SPLIT_CODES 1024
#define SPLIT_BYTES (SPLIT_CODES * DDIM * 2)   // 512 KB of bf16 panels per split
#define PANEL_CODES 64
#define PANELS_PER_SPLIT 16   // 1024 / 64
#define PANEL_BYTES 32768     // 64 codes x 256 dims x 2B (= 2 contiguous 16KB tiles)
#define ROWS_PER_BLOCK 128    // 4 waves x 32 rows

typedef __attribute__((ext_vector_type(8))) short short8v;
typedef __attribute__((ext_vector_type(4))) float float4v;
typedef unsigned int u32;
typedef unsigned short u16;

// ---- RNE float -> bf16 ----
__device__ __forceinline__ short f2bf(float x) {
    u32 u = __float_as_uint(x);
    u = u + 0x7fffu + ((u >> 16) & 1u);
    return (short)(u >> 16);
}

// ---- async global->LDS, 16B per lane; lds dst = wave-uniform base + lane*16 ----
__device__ __forceinline__ void gload_lds16(const void* g, void* l) {
    __builtin_amdgcn_global_load_lds(
        (const __attribute__((address_space(1))) u32*)g,
        (__attribute__((address_space(3))) u32*)l, 16, 0, 0);
}

// ---- numpy pairwise-sum simulation (bit-faithful for n=256 contiguous) ----
__device__ __forceinline__ float np_sq_chain(const float* v, int lane) {
    #pragma clang fp contract(off)
    const int half = lane >> 3, j = lane & 7;
    const float* base = v + half * 128 + j;
    float x = base[0];
    float c = x * x;
    #pragma unroll
    for (int m = 1; m < 16; ++m) {
        float y = base[8 * m];
        float s = y * y;
        c = c + s;
    }
    return c;
}

__device__ __forceinline__ float np_combine16(const float* c) {
    #pragma clang fp contract(off)
    float L = ((c[0] + c[1]) + (c[2] + c[3])) + ((c[4] + c[5]) + (c[6] + c[7]));
    float R = ((c[8] + c[9]) + (c[10] + c[11])) + ((c[12] + c[13]) + (c[14] + c[15]));
    return L + R;
}

// ---- top-3 insertion (strict <, preserves first-insertion on ties) ----
__device__ __forceinline__ void ins3(float m, int k,
                                     float& v0, float& v1, float& v2,
                                     int& i0, int& i1, int& i2) {
    if (m < v0)      { v2 = v1; i2 = i1; v1 = v0; i1 = i0; v0 = m; i0 = k; }
    else if (m < v1) { v2 = v1; i2 = i1; v1 = m;  i1 = k; }
    else if (m < v2) { v2 = m;  i2 = k; }
}

// ---------------- kernel 2: numpy-faithful code norms ||e_k||^2 (+ zero counts) ----------------
__global__ void code_norms_np_kernel(const float* __restrict__ e, float* __restrict__ e2,
                                     int* __restrict__ counts) {
    __shared__ float buf[DDIM];
    __shared__ float ch[16];
    int k = blockIdx.x;
    int t = threadIdx.x;  // 64 threads = 1 wave
    if (t == 0) counts[k] = 0;   // fused zero_counts (grid == K)
    float4 v = *(const float4*)&e[(size_t)k * DDIM + t * 4];
    *(float4*)&buf[t * 4] = v;
    __syncthreads();
    if (t < 16) ch[t] = np_sq_chain(buf, t);
    __syncthreads();
    if (t == 0) e2[k] = np_combine16(ch);
}

// ---------------- kernel 2b: convert e -> bf16 panel layout ----------------
// ebf_p[tile=k/32][d8=0..31][r=k%32][8 shorts]; tile = 16KB contiguous.
__global__ void convert_permute_e_kernel(const float* __restrict__ e, char* __restrict__ ebf_p) {
    int id = blockIdx.x * 256 + threadIdx.x;   // id = k*32 + d8, total K*32
    int k = id >> 5, d8 = id & 31;
    const float* s = &e[(size_t)k * DDIM + d8 * 8];
    float4 f0 = *(const float4*)s;
    float4 f1 = *(const float4*)(s + 4);
    short8v v;
    v[0] = f2bf(f0.x); v[1] = f2bf(f0.y); v[2] = f2bf(f0.z); v[3] = f2bf(f0.w);
    v[4] = f2bf(f1.x); v[5] = f2bf(f1.y); v[6] = f2bf(f1.z); v[7] = f2bf(f1.w);
    *(short8v*)(ebf_p + ((size_t)(k >> 5) << 14) + d8 * 512 + (k & 31) * 16) = v;
}

// ---------------- kernel 3: 2D-blocked GEMM (m97-style) with fused top-3 ----------------
// ARITHMETIC-INTENSITY FIX (round 10). Ten structures all floored at ~264-290us
// with every pipe idle. The invariant none of them changed: ~1 KB of operand
// bytes moved PER MFMA PER WAVE (codes re-read per 16-row wave). Observed
// effective operand BW ~13 B/cy/CU ~= the measured per-CU global-load service
// rate (m13) -> operand delivery was the binding resource all along, and the
// fix is REUSE, not scheduling. This is the verified m97 GEMM shape:
//   - 128 z-rows resident in LDS as bf16 panels (64 KB, staged once/block);
//   - 64-code panels double-buffered (2x32 KB) via gload_lds, counted
//     vmcnt(8) ledger (R5-verified pattern), 2 barriers/panel;
//   - 4 waves; wave = 32 rows x 64 codes = 8 accs; per K-step 6 ds_read_b128
//     feed 8 MFMAs (2x less LDS traffic/MFMA, 8x less global traffic);
//   - fused epilogue folds 64 codes into per-row top-3 (same fragment
//     recipes, score math, quad partition (codes == q*4+r mod 16), and ins3
//     semantics as the verified rounds; visit order ascending per quad).
// Grid (N/128, 2 splits) = 512 blocks; LDS 132 KB -> 1 block/CU (ILP-fed).
__global__ __launch_bounds__(256, 1)
void vq_cand_kernel(const float* __restrict__ z, const char* __restrict__ ebf_p,
                    const float* __restrict__ e2, float* __restrict__ cand_v,
                    u16* __restrict__ cand_i, int N) {
    __shared__ __align__(16) char cpan[2][PANEL_BYTES];  // 64 KB code dbuf
    __shared__ __align__(16) char zlds[65536];           // 8 x [32 d8][16 r][16B] panels
    __shared__ float e2s[1024];
    const int t    = threadIdx.x;
    const int w    = t >> 6;        // wave 0..3
    const int lane = t & 63;
    const int quad = lane >> 4;
    const int l15  = lane & 15;
    const int s    = blockIdx.y;
    const int rw0  = blockIdx.x * ROWS_PER_BLOCK;

    const char* cbase = ebf_p + (size_t)s * SPLIT_BYTES;

    // ---- stage z: 128 rows -> bf16 panels (each thread 16 (row,c8) units) ----
    // unit u = t + i*256: row = u>>5, c = u&31 -> 32-lane groups read 1KB
    // contiguous fp32; write zlds[row>>4][c][row&15] (same layout as verified
    // zf fragments -> bit-identical MFMA inputs).
    #pragma unroll
    for (int i = 0; i < 16; ++i) {
        int u = t + i * 256;
        int row = u >> 5, c = u & 31;
        const float* src = &z[(size_t)(rw0 + row) * DDIM + c * 8];
        float4 f0 = *(const float4*)src;
        float4 f1 = *(const float4*)(src + 4);
        short8v v;
        v[0] = f2bf(f0.x); v[1] = f2bf(f0.y); v[2] = f2bf(f0.z); v[3] = f2bf(f0.w);
        v[4] = f2bf(f1.x); v[5] = f2bf(f1.y); v[6] = f2bf(f1.z); v[7] = f2bf(f1.w);
        *(short8v*)(zlds + (row >> 4) * 8192 + c * 256 + (row & 15) * 16) = v;
    }
    // e2 split -> LDS (4 per thread)
    e2s[t]       = e2[s * 1024 + t];
    e2s[t + 256] = e2[s * 1024 + 256 + t];
    e2s[t + 512] = e2[s * 1024 + 512 + t];
    e2s[t + 768] = e2[s * 1024 + 768 + t];

    // ---- issue panel 0 and 1 code gloads LAST (stay in flight across barrier) ----
#define STAGE_PANEL(P, BUF)                                                  \
    {                                                                        \
        const char* sp_ = cbase + (size_t)(P) * PANEL_BYTES;                 \
        char* dp_ = cpan[BUF];                                               \
        _Pragma("unroll")                                                    \
        for (int j = 0; j < 8; ++j)                                          \
            gload_lds16(sp_ + j * 4096 + t * 16, dp_ + j * 4096 + t * 16);   \
    }
    STAGE_PANEL(0, 0)
    STAGE_PANEL(1, 1)

    // z/e2 ds_writes visible to all waves; code gloads (16) remain in flight
    asm volatile("s_waitcnt lgkmcnt(0)" ::: "memory");
    __builtin_amdgcn_s_barrier();

    // per-lane top-3: m=0 -> row rw0+w*32+l15, m=1 -> row rw0+w*32+16+l15
    float tv00 = 3.4e38f, tv01 = 3.4e38f, tv02 = 3.4e38f;
    int   ti00 = 0x7fff,  ti01 = 0x7fff,  ti02 = 0x7fff;
    float tv10 = 3.4e38f, tv11 = 3.4e38f, tv12 = 3.4e38f;
    int   ti10 = 0x7fff,  ti11 = 0x7fff,  ti12 = 0x7fff;

    const char* zq = zlds + w * 16384 + quad * 256 + l15 * 16;  // groups 2w, 2w+1

    // vmcnt ledger (8 gloads/panel): entering panel p outstanding = {p:8, p+1:8}
    // -> vmcnt(8) completes p; restage issues after barrier2; last panel waits 0.
    #pragma unroll 1
    for (int p = 0; p < PANELS_PER_SPLIT; ++p) {
        if (p < PANELS_PER_SPLIT - 1)
            asm volatile("s_waitcnt vmcnt(8)" ::: "memory");
        else
            asm volatile("s_waitcnt vmcnt(0)" ::: "memory");
        __builtin_amdgcn_s_barrier();   // panel p data landed in LDS

        const char* es = cpan[p & 1];
        const char* aq = es + quad * 512 + l15 * 16;

        float4v c00 = (float4v)0.0f, c01 = (float4v)0.0f,
                c02 = (float4v)0.0f, c03 = (float4v)0.0f;
        float4v c10 = (float4v)0.0f, c11 = (float4v)0.0f,
                c12 = (float4v)0.0f, c13 = (float4v)0.0f;

        #pragma unroll
        for (int kk = 0; kk < 8; ++kk) {
            const char* ak = aq + kk * 2048;
            const char* zk = zq + kk * 1024;
            short8v A0 = *(const short8v*)(ak);                // codes p*64 +  0..15
            short8v A1 = *(const short8v*)(ak + 256);          // codes 16..31
            short8v A2 = *(const short8v*)(ak + 16384);        // codes 32..47
            short8v A3 = *(const short8v*)(ak + 16384 + 256);  // codes 48..63
            short8v B0 = *(const short8v*)(zk);                // rows w*32 +  0..15
            short8v B1 = *(const short8v*)(zk + 8192);         // rows 16..31
            c00 = __builtin_amdgcn_mfma_f32_16x16x32_bf16(A0, B0, c00, 0, 0, 0);
            c01 = __builtin_amdgcn_mfma_f32_16x16x32_bf16(A1, B0, c01, 0, 0, 0);
            c02 = __builtin_amdgcn_mfma_f32_16x16x32_bf16(A2, B0, c02, 0, 0, 0);
            c03 = __builtin_amdgcn_mfma_f32_16x16x32_bf16(A3, B0, c03, 0, 0, 0);
            c10 = __builtin_amdgcn_mfma_f32_16x16x32_bf16(A0, B1, c10, 0, 0, 0);
            c11 = __builtin_amdgcn_mfma_f32_16x16x32_bf16(A1, B1, c11, 0, 0, 0);
            c12 = __builtin_amdgcn_mfma_f32_16x16x32_bf16(A2, B1, c12, 0, 0, 0);
            c13 = __builtin_amdgcn_mfma_f32_16x16x32_bf16(A3, B1, c13, 0, 0, 0);
        }

        // epilogue: m(k)=e2[k]-2S folded into per-row top-3; per quad-stream
        // the visit order is ascending codes (n asc, r asc, panels asc).
        const int pb = p * PANEL_CODES;
        const int kb = s * SPLIT_CODES + pb;
#define FOLD4(ACC, EOFF, V0, V1, V2, I0, I1, I2)                             \
        {                                                                    \
            float4 E = *(const float4*)&e2s[pb + (EOFF) + quad * 4];         \
            float mm;                                                        \
            mm = fmaf(-2.0f, ACC[0], E.x); ins3(mm, kb + (EOFF) + quad * 4 + 0, V0, V1, V2, I0, I1, I2); \
            mm = fmaf(-2.0f, ACC[1], E.y); ins3(mm, kb + (EOFF) + quad * 4 + 1, V0, V1, V2, I0, I1, I2); \
            mm = fmaf(-2.0f, ACC[2], E.z); ins3(mm, kb + (EOFF) + quad * 4 + 2, V0, V1, V2, I0, I1, I2); \
            mm = fmaf(-2.0f, ACC[3], E.w); ins3(mm, kb + (EOFF) + quad * 4 + 3, V0, V1, V2, I0, I1, I2); \
        }
        FOLD4(c00,  0, tv00, tv01, tv02, ti00, ti01, ti02)
        FOLD4(c01, 16, tv00, tv01, tv02, ti00, ti01, ti02)
        FOLD4(c02, 32, tv00, tv01, tv02, ti00, ti01, ti02)
        FOLD4(c03, 48, tv00, tv01, tv02, ti00, ti01, ti02)
        FOLD4(c10,  0, tv10, tv11, tv12, ti10, ti11, ti12)
        FOLD4(c11, 16, tv10, tv11, tv12, ti10, ti11, ti12)
        FOLD4(c12, 32, tv10, tv11, tv12, ti10, ti11, ti12)
        FOLD4(c13, 48, tv10, tv11, tv12, ti10, ti11, ti12)
#undef FOLD4

        // all waves done reading cpan[p&1] before it is refilled
        asm volatile("s_waitcnt lgkmcnt(0)" ::: "memory");
        __builtin_amdgcn_s_barrier();

        if (p + 2 < PANELS_PER_SPLIT)
            STAGE_PANEL(p + 2, p & 1)
    }
#undef STAGE_PANEL

    // ---- cross-quad merge (per m-state): 4 quads x top-3 -> split top-3 ----
#define MERGE_STORE(V0, V1, V2, I0, I1, I2, MOFF)                            \
    {                                                                        \
        float bm0 = 3.4e38f, bm1 = 3.4e38f, bm2 = 3.4e38f;                   \
        int   bk0 = 0x7fff,  bk1 = 0x7fff,  bk2 = 0x7fff;                    \
        _Pragma("unroll")                                                    \
        for (int q = 0; q < 4; ++q) {                                        \
            int src = l15 + q * 16;                                          \
            float m0 = __shfl(V0, src); int k0 = __shfl(I0, src);            \
            float m1 = __shfl(V1, src); int k1 = __shfl(I1, src);            \
            float m2 = __shfl(V2, src); int k2 = __shfl(I2, src);            \
            ins3(m0, k0, bm0, bm1, bm2, bk0, bk1, bk2);                      \
            ins3(m1, k1, bm0, bm1, bm2, bk0, bk1, bk2);                      \
            ins3(m2, k2, bm0, bm1, bm2, bk0, bk1, bk2);                      \
        }                                                                    \
        if (quad == 0) {                                                     \
            int row = rw0 + w * 32 + (MOFF) + l15;                           \
            size_t base = ((size_t)s * N + row) * 3;                         \
            cand_v[base]     = bm0;  cand_i[base]     = (u16)bk0;            \
            cand_v[base + 1] = bm1;  cand_i[base + 1] = (u16)bk1;            \
            cand_v[base + 2] = bm2;  cand_i[base + 2] = (u16)bk2;            \
        }                                                                    \
    }
    MERGE_STORE(tv00, tv01, tv02, ti00, ti01, ti02, 0)
    MERGE_STORE(tv10, tv11, tv12, ti10, ti11, ti12, 16)
#undef MERGE_STORE
}

// ---------------- kernel 4: prefilter + np-faithful re-rank + gather + loss ----------------
// One wave per row. Pool = 6 (2 splits x top-3) sorted by (value,idx); exact
// fp64 dots on 6, numpy-fp32-faithful distance ranking, fused gather+partials.
__global__ void refine_fused_kernel(const float* __restrict__ z, const float* __restrict__ e,
                                    const float* __restrict__ e2np,
                                    const float* __restrict__ cand_v,
                                    const u16* __restrict__ cand_i,
                                    int* __restrict__ counts, float* __restrict__ partials,
                                    float* __restrict__ out_zq, float* __restrict__ out_idx,
                                    int N) {
    __shared__ float buf[4][DDIM];
    __shared__ float ch[4][16];
    __shared__ float wsum[4];
    const int w = threadIdx.x >> 6;
    const int t = threadIdx.x & 63;
    const int n = blockIdx.x * 4 + w;

    float4 zv = *(const float4*)&z[(size_t)n * DDIM + t * 4];
    *(float4*)&buf[w][t * 4] = zv;
    __syncthreads();
    if (t < 16) ch[w][t] = np_sq_chain(buf[w], t);
    __syncthreads();

    // ---- pool: 6 candidates, (value,idx)-sorted insertion ----
    float bv[6]; int bi[6];
    #pragma unroll
    for (int c = 0; c < 6; ++c) { bv[c] = 3.4e38f; bi[c] = 0x7fffffff; }
    #pragma unroll
    for (int c = 0; c < 6; ++c) {
        int sp = c / 3, j = c - sp * 3;
        size_t off = ((size_t)sp * N + n) * 3 + j;
        float v  = cand_v[off];
        int   id = (int)cand_i[off];
        #pragma unroll
        for (int x = 0; x < 6; ++x) {
            if (v < bv[x] || (v == bv[x] && id < bi[x])) {
                for (int d = 5; d > x; --d) { bv[d] = bv[d - 1]; bi[d] = bi[d - 1]; }
                bv[x] = v; bi[x] = id;
                break;
            }
        }
    }

    float dotf[6];
    #pragma unroll
    for (int c = 0; c < 6; ++c) {
        int k = bi[c];
        float4 ev = *(const float4*)&e[(size_t)k * DDIM + t * 4];
        double p = (double)zv.x * (double)ev.x + (double)zv.y * (double)ev.y
                 + (double)zv.z * (double)ev.z + (double)zv.w * (double)ev.w;
        #pragma unroll
        for (int o = 32; o > 0; o >>= 1) p += __shfl_down(p, o);
        dotf[c] = (float)p;   // correctly-rounded fp32 of exact dot
    }

    int bk = 0;
    if (t == 0) {
        #pragma clang fp contract(off)
        float sx = np_combine16(ch[w]);
        float bd = 3.4e38f;
        bk = 0x7fffffff;
        #pragma unroll
        for (int c = 0; c < 6; ++c) {
            float twod = 2.0f * dotf[c];
            float t1 = sx - twod;
            float d2v = t1 + e2np[bi[c]];
            d2v = fmaxf(d2v, 0.0f);
            float d = sqrtf(d2v);
            if (d < bd || (d == bd && bi[c] < bk)) { bd = d; bk = bi[c]; }
        }
    }
    int wk = __shfl(bk, 0);

    float4 ev = *(const float4*)&e[(size_t)wk * DDIM + t * 4];
    *(float4*)&out_zq[(size_t)n * DDIM + t * 4] = ev;
    float dx = zv.x - ev.x, dy = zv.y - ev.y, dz = zv.z - ev.z, dw = zv.w - ev.w;
    float sq = dx * dx + dy * dy + dz * dz + dw * dw;
    #pragma unroll
    for (int o = 32; o > 0; o >>= 1) sq += __shfl_down(sq, o);
    if (t == 0) {
        wsum[w] = sq;
        atomicAdd(&counts[wk], 1);
        out_idx[n] = (float)wk;
    }
    __syncthreads();
    if (threadIdx.x == 0)
        partials[blockIdx.x] = wsum[0] + wsum[1] + wsum[2] + wsum[3];
}

// ---------------- kernel 5: finalize loss ----------------
__global__ void finalize_kernel(const int* __restrict__ counts, const float* __restrict__ partials,
                                float* __restrict__ out_loss, int K, int NB,
                                float invN, float invND) {
    int t = threadIdx.x;
    double ent = 0.0, sq = 0.0;
    for (int k = t; k < K; k += 256) {
        float p = (float)counts[k] * invN;
        ent += (double)(p * logf(p + 1e-10f));
    }
    for (int i = t; i < NB; i += 256) sq += (double)partials[i];
    #pragma unroll
    for (int o = 32; o > 0; o >>= 1) {
        ent += __shfl_down(ent, o);
        sq  += __shfl_down(sq, o);
    }
    __shared__ double e4[4], s4[4];
    if ((t & 63) == 0) { e4[t >> 6] = ent; s4[t >> 6] = sq; }
    __syncthreads();
    if (t == 0) {
        double esum = e4[0] + e4[1] + e4[2] + e4[3];
        double ssum = s4[0] + s4[1] + s4[2] + s4[3];
        float perp = expf((float)(-esum));
        float mean = (float)ssum * invND;
        out_loss[0] = 1.25f * mean - 0.01f * perp;
    }
}

extern "C" void kernel_launch(void* const* d_in, const int* in_sizes, int n_in,
                              void* d_out, int out_size, void* d_ws, size_t ws_size,
                              hipStream_t stream) {
    const float* z = (const float*)d_in[0];
    const float* e = (const float*)d_in[1];
    const int N = in_sizes[0] / DDIM;   // 32768
    const int K = in_sizes[1] / DDIM;   // 2048

    float* out      = (float*)d_out;
    float* out_zq   = out;
    float* out_loss = out + (size_t)N * DDIM;
    float* out_idx  = out_loss + 1;

    // ws layout (bytes):
    //   counts[K]            @ 0        (8 KB)
    //   e2np[K]              @ 8192     (8 KB)
    //   partials[N/4]        @ 16384    (32 KB)
    //   cand_v[2][N][3] f32  @ 49152    (768 KB)
    //   cand_i[2][N][3] u16  @ 835584   (384 KB)
    //   ebf_p (1 MB panels)  @ 1228800  -> total ~2.2 MB
    int*   counts   = (int*)d_ws;
    float* e2np     = (float*)((char*)d_ws + 8192);
    float* partials = (float*)((char*)d_ws + 16384);
    float* cand_v   = (float*)((char*)d_ws + 49152);
    u16*   cand_i   = (u16*)((char*)d_ws + 835584);
    char*  ebf_p    = (char*)d_ws + 1228800;

    code_norms_np_kernel<<<K, 64, 0, stream>>>(e, e2np, counts);
    convert_permute_e_kernel<<<K * 32 / 256, 256, 0, stream>>>(e, ebf_p);
    vq_cand_kernel<<<dim3(N / ROWS_PER_BLOCK, NSPLIT), 256, 0, stream>>>(z, ebf_p, e2np,
                                                                         cand_v, cand_i, N);
    refine_fused_kernel<<<N / 4, 256, 0, stream>>>(z, e, e2np, cand_v, cand_i,
                                                   counts, partials, out_zq, out_idx, N);
    finalize_kernel<<<1, 256, 0, stream>>>(counts, partials, out_loss, K, N / 4,
                                           1.0f / (float)N, 1.0f / (float)(N * DDIM));
}

// Round 11
// 472.666 us; speedup vs baseline: 1.4103x; 1.4103x over previous
//
#include <hip/hip_runtime.h>
#include <math.h>

#define DDIM 256
#define NSPLIT 2
#define TILES_PER_SPLIT 32   // 32 tiles x 32 codes = 1024 codes per split
#define TILE_CODES 32
#define TILE_BYTES 16384     // 32 codes x 256 dims x 2B (panel layout)
#define ROWS_PER_BLOCK 128   // 8 waves x 16 rows

typedef __attribute__((ext_vector_type(8))) short short8v;
typedef __attribute__((ext_vector_type(4))) float float4v;
typedef unsigned int u32;
typedef unsigned short u16;

// ---- RNE float -> bf16 ----
__device__ __forceinline__ short f2bf(float x) {
    u32 u = __float_as_uint(x);
    u = u + 0x7fffu + ((u >> 16) & 1u);
    return (short)(u >> 16);
}

// ---- numpy pairwise-sum simulation (bit-faithful for n=256 contiguous) ----
__device__ __forceinline__ float np_sq_chain(const float* v, int lane) {
    #pragma clang fp contract(off)
    const int half = lane >> 3, j = lane & 7;
    const float* base = v + half * 128 + j;
    float x = base[0];
    float c = x * x;
    #pragma unroll
    for (int m = 1; m < 16; ++m) {
        float y = base[8 * m];
        float s = y * y;
        c = c + s;
    }
    return c;
}

__device__ __forceinline__ float np_combine16(const float* c) {
    #pragma clang fp contract(off)
    float L = ((c[0] + c[1]) + (c[2] + c[3])) + ((c[4] + c[5]) + (c[6] + c[7]));
    float R = ((c[8] + c[9]) + (c[10] + c[11])) + ((c[12] + c[13]) + (c[14] + c[15]));
    return L + R;
}

// ---- top-3 insertion (strict <, preserves first-insertion on ties) ----
__device__ __forceinline__ void ins3(float m, int k,
                                     float& v0, float& v1, float& v2,
                                     int& i0, int& i1, int& i2) {
    if (m < v0)      { v2 = v1; i2 = i1; v1 = v0; i1 = i0; v0 = m; i0 = k; }
    else if (m < v1) { v2 = v1; i2 = i1; v1 = m;  i1 = k; }
    else if (m < v2) { v2 = m;  i2 = k; }
}

// ---------------- kernel 2: numpy-faithful code norms ||e_k||^2 (+ zero counts) ----------------
__global__ void code_norms_np_kernel(const float* __restrict__ e, float* __restrict__ e2,
                                     int* __restrict__ counts) {
    __shared__ float buf[DDIM];
    __shared__ float ch[16];
    int k = blockIdx.x;
    int t = threadIdx.x;  // 64 threads = 1 wave
    if (t == 0) counts[k] = 0;   // fused zero_counts (grid == K)
    float4 v = *(const float4*)&e[(size_t)k * DDIM + t * 4];
    *(float4*)&buf[t * 4] = v;
    __syncthreads();
    if (t < 16) ch[t] = np_sq_chain(buf, t);
    __syncthreads();
    if (t == 0) e2[k] = np_combine16(ch);
}

// ---------------- kernel 2b: convert e -> bf16 panel layout ----------------
// ebf_p[tile=k/32][d8=0..31][r=k%32][8 shorts]; tile = 16KB contiguous.
__global__ void convert_permute_e_kernel(const float* __restrict__ e, char* __restrict__ ebf_p) {
    int id = blockIdx.x * 256 + threadIdx.x;   // id = k*32 + d8, total K*32
    int k = id >> 5, d8 = id & 31;
    const float* s = &e[(size_t)k * DDIM + d8 * 8];
    float4 f0 = *(const float4*)s;
    float4 f1 = *(const float4*)(s + 4);
    short8v v;
    v[0] = f2bf(f0.x); v[1] = f2bf(f0.y); v[2] = f2bf(f0.z); v[3] = f2bf(f0.w);
    v[4] = f2bf(f1.x); v[5] = f2bf(f1.y); v[6] = f2bf(f1.z); v[7] = f2bf(f1.w);
    *(short8v*)(ebf_p + ((size_t)(k >> 5) << 14) + d8 * 512 + (k & 31) * 16) = v;
}

// ---------------- kernel 3: R9 + 1-tile REGISTER LOOKAHEAD pipeline ----------------
// EXPOSED-LATENCY FIX (round 11). Eleven structures bracketed everything else:
// scratch eliminated (R10: VGPR=132, WRITE=10MB -> SLOWER), operand traffic
// varied 8x with no effect (R1: 262MB@277us vs R8: 2.1GB@264us), sync varied
// lockstep->none with no effect, occupancy mattered only below ~4 waves/SIMD.
// Surviving invariant: every round's `#pragma unroll 1` tile loop issues,
// waits, and consumes its 16 operand loads WITHIN the iteration -> ~2-5kcy of
// exposed L2 latency per tile per wave that <=4 waves/SIMD cannot cover. R9
// proved the registers exist (512 budget, 40 used) -- no round used them to
// PREFETCH. Fix: double-buffer the 16 code loads in NAMED short8v sets A/B
// (rule #20 safe) with a hand unroll-2 pipeline:
//   load(B,tt+1) -> compute(A,tt) -> load(A,tt+2) -> compute(B,tt+1)
// The compiler's auto-waitcnt becomes a counted wait (B completes while A's
// loads fly) -- AITER's interleave in plain HIP. Everything else = R9 exactly
// (scores, visit order, tie semantics bit-identical; passed twice).
// Falsifiable: VGPR 40 -> 150-220. If VGPR rises but dur stays ~260us, the
// floor is environmental (clock) -> vq_cand declared walled, pivot to refine.
__global__ __launch_bounds__(512, 1)
void vq_cand_kernel(const float* __restrict__ z, const char* __restrict__ ebf_p,
                    const float* __restrict__ e2, float* __restrict__ cand_v,
                    u16* __restrict__ cand_i, int N) {
    __shared__ float e2s[1024];
    const int t    = threadIdx.x;
    const int w    = t >> 6;        // wave 0..7
    const int lane = t & 63;
    const int quad = lane >> 4;
    const int l15  = lane & 15;
    const int s    = blockIdx.y;
    const int rw   = blockIdx.x * ROWS_PER_BLOCK + w * 16;   // this wave's 16 rows

    // e2 for this split -> LDS once (512 threads x 2 floats)
    e2s[t]       = e2[s * 1024 + t];
    e2s[t + 512] = e2[s * 1024 + 512 + t];

    // ---- persistent z fragments: 16 rows x 256 dims per wave, NAMED scalars ----
    short8v zf0, zf1, zf2, zf3, zf4, zf5, zf6, zf7;
    {
        const float* zr = &z[(size_t)(rw + l15) * DDIM];
#define LOADZ(I, DST)                                                        \
        {                                                                    \
            int d0 = (I) * 32 + quad * 8;                                    \
            float4 f0 = *(const float4*)&zr[d0];                             \
            float4 f1 = *(const float4*)&zr[d0 + 4];                         \
            short8v v;                                                       \
            v[0] = f2bf(f0.x); v[1] = f2bf(f0.y);                            \
            v[2] = f2bf(f0.z); v[3] = f2bf(f0.w);                            \
            v[4] = f2bf(f1.x); v[5] = f2bf(f1.y);                            \
            v[6] = f2bf(f1.z); v[7] = f2bf(f1.w);                            \
            DST = v;                                                         \
        }
        LOADZ(0, zf0) LOADZ(1, zf1) LOADZ(2, zf2) LOADZ(3, zf3)
        LOADZ(4, zf4) LOADZ(5, zf5) LOADZ(6, zf6) LOADZ(7, zf7)
#undef LOADZ
    }

    __syncthreads();   // e2s ready; the ONLY barrier in this kernel

    float v0 = 3.4e38f, v1 = 3.4e38f, v2 = 3.4e38f;
    int   i0 = 0x7fff,  i1 = 0x7fff,  i2 = 0x7fff;

    const char* sbase = ebf_p + (size_t)s * TILES_PER_SPLIT * TILE_BYTES
                      + quad * 512 + l15 * 16;

    // ---- named double-buffer register sets for the 16 per-tile code loads ----
    short8v Aa0, Ab0, Aa1, Ab1, Aa2, Ab2, Aa3, Ab3,
            Aa4, Ab4, Aa5, Ab5, Aa6, Ab6, Aa7, Ab7;
    short8v Ba0, Bb0, Ba1, Bb1, Ba2, Bb2, Ba3, Bb3,
            Ba4, Bb4, Ba5, Bb5, Ba6, Bb6, Ba7, Bb7;

#define LOAD_TILE(P, TT)                                                     \
    {                                                                        \
        const char* tg_ = sbase + (size_t)(TT) * TILE_BYTES;                 \
        P##a0 = *(const short8v*)(tg_ + 0 * 2048);                           \
        P##b0 = *(const short8v*)(tg_ + 0 * 2048 + 256);                     \
        P##a1 = *(const short8v*)(tg_ + 1 * 2048);                           \
        P##b1 = *(const short8v*)(tg_ + 1 * 2048 + 256);                     \
        P##a2 = *(const short8v*)(tg_ + 2 * 2048);                           \
        P##b2 = *(const short8v*)(tg_ + 2 * 2048 + 256);                     \
        P##a3 = *(const short8v*)(tg_ + 3 * 2048);                           \
        P##b3 = *(const short8v*)(tg_ + 3 * 2048 + 256);                     \
        P##a4 = *(const short8v*)(tg_ + 4 * 2048);                           \
        P##b4 = *(const short8v*)(tg_ + 4 * 2048 + 256);                     \
        P##a5 = *(const short8v*)(tg_ + 5 * 2048);                           \
        P##b5 = *(const short8v*)(tg_ + 5 * 2048 + 256);                     \
        P##a6 = *(const short8v*)(tg_ + 6 * 2048);                           \
        P##b6 = *(const short8v*)(tg_ + 6 * 2048 + 256);                     \
        P##a7 = *(const short8v*)(tg_ + 7 * 2048);                           \
        P##b7 = *(const short8v*)(tg_ + 7 * 2048 + 256);                     \
    }

#define COMPUTE_TILE(P, TT)                                                  \
    {                                                                        \
        float4v acc0 = (float4v)0.0f, acc1 = (float4v)0.0f;                  \
        acc0 = __builtin_amdgcn_mfma_f32_16x16x32_bf16(P##a0, zf0, acc0, 0, 0, 0); \
        acc1 = __builtin_amdgcn_mfma_f32_16x16x32_bf16(P##b0, zf0, acc1, 0, 0, 0); \
        acc0 = __builtin_amdgcn_mfma_f32_16x16x32_bf16(P##a1, zf1, acc0, 0, 0, 0); \
        acc1 = __builtin_amdgcn_mfma_f32_16x16x32_bf16(P##b1, zf1, acc1, 0, 0, 0); \
        acc0 = __builtin_amdgcn_mfma_f32_16x16x32_bf16(P##a2, zf2, acc0, 0, 0, 0); \
        acc1 = __builtin_amdgcn_mfma_f32_16x16x32_bf16(P##b2, zf2, acc1, 0, 0, 0); \
        acc0 = __builtin_amdgcn_mfma_f32_16x16x32_bf16(P##a3, zf3, acc0, 0, 0, 0); \
        acc1 = __builtin_amdgcn_mfma_f32_16x16x32_bf16(P##b3, zf3, acc1, 0, 0, 0); \
        acc0 = __builtin_amdgcn_mfma_f32_16x16x32_bf16(P##a4, zf4, acc0, 0, 0, 0); \
        acc1 = __builtin_amdgcn_mfma_f32_16x16x32_bf16(P##b4, zf4, acc1, 0, 0, 0); \
        acc0 = __builtin_amdgcn_mfma_f32_16x16x32_bf16(P##a5, zf5, acc0, 0, 0, 0); \
        acc1 = __builtin_amdgcn_mfma_f32_16x16x32_bf16(P##b5, zf5, acc1, 0, 0, 0); \
        acc0 = __builtin_amdgcn_mfma_f32_16x16x32_bf16(P##a6, zf6, acc0, 0, 0, 0); \
        acc1 = __builtin_amdgcn_mfma_f32_16x16x32_bf16(P##b6, zf6, acc1, 0, 0, 0); \
        acc0 = __builtin_amdgcn_mfma_f32_16x16x32_bf16(P##a7, zf7, acc0, 0, 0, 0); \
        acc1 = __builtin_amdgcn_mfma_f32_16x16x32_bf16(P##b7, zf7, acc1, 0, 0, 0); \
        const int kloc  = (TT) * TILE_CODES;                                 \
        const int kbase = s * 1024 + kloc;                                   \
        float4 e2a = *(const float4*)&e2s[kloc + quad * 4];                  \
        float4 e2b = *(const float4*)&e2s[kloc + 16 + quad * 4];             \
        float m;                                                             \
        m = fmaf(-2.0f, acc0[0], e2a.x); ins3(m, kbase + quad * 4 + 0,      v0, v1, v2, i0, i1, i2); \
        m = fmaf(-2.0f, acc1[0], e2b.x); ins3(m, kbase + 16 + quad * 4 + 0, v0, v1, v2, i0, i1, i2); \
        m = fmaf(-2.0f, acc0[1], e2a.y); ins3(m, kbase + quad * 4 + 1,      v0, v1, v2, i0, i1, i2); \
        m = fmaf(-2.0f, acc1[1], e2b.y); ins3(m, kbase + 16 + quad * 4 + 1, v0, v1, v2, i0, i1, i2); \
        m = fmaf(-2.0f, acc0[2], e2a.z); ins3(m, kbase + quad * 4 + 2,      v0, v1, v2, i0, i1, i2); \
        m = fmaf(-2.0f, acc1[2], e2b.z); ins3(m, kbase + 16 + quad * 4 + 2, v0, v1, v2, i0, i1, i2); \
        m = fmaf(-2.0f, acc0[3], e2a.w); ins3(m, kbase + quad * 4 + 3,      v0, v1, v2, i0, i1, i2); \
        m = fmaf(-2.0f, acc1[3], e2b.w); ins3(m, kbase + 16 + quad * 4 + 3, v0, v1, v2, i0, i1, i2); \
    }

    // ---- software pipeline: prefetch tile 0, then 2-stage rotation ----
    LOAD_TILE(A, 0)
    #pragma unroll 1
    for (int tt = 0; tt < TILES_PER_SPLIT; tt += 2) {
        LOAD_TILE(B, tt + 1)          // tt+1 <= 31 always valid
        COMPUTE_TILE(A, tt)           // waits only on A; B's loads in flight
        if (tt + 2 < TILES_PER_SPLIT)
            LOAD_TILE(A, tt + 2)
        COMPUTE_TILE(B, tt + 1)       // waits only on B; A's loads in flight
    }
#undef LOAD_TILE
#undef COMPUTE_TILE

    // ---- cross-quad merge via shuffles: 4 quads x top-3 -> split top-3 ----
    {
        float bm0 = 3.4e38f, bm1 = 3.4e38f, bm2 = 3.4e38f;
        int   bk0 = 0x7fff,  bk1 = 0x7fff,  bk2 = 0x7fff;
        #pragma unroll
        for (int q = 0; q < 4; ++q) {
            int src = l15 + q * 16;
            float m0 = __shfl(v0, src); int k0 = __shfl(i0, src);
            float m1 = __shfl(v1, src); int k1 = __shfl(i1, src);
            float m2 = __shfl(v2, src); int k2 = __shfl(i2, src);
            ins3(m0, k0, bm0, bm1, bm2, bk0, bk1, bk2);
            ins3(m1, k1, bm0, bm1, bm2, bk0, bk1, bk2);
            ins3(m2, k2, bm0, bm1, bm2, bk0, bk1, bk2);
        }
        // split-major layout cand[s][n][3]: contiguous per-block writes
        if (quad == 0) {
            size_t base = ((size_t)s * N + (rw + l15)) * 3;
            cand_v[base]     = bm0;  cand_i[base]     = (u16)bk0;
            cand_v[base + 1] = bm1;  cand_i[base + 1] = (u16)bk1;
            cand_v[base + 2] = bm2;  cand_i[base + 2] = (u16)bk2;
        }
    }
}

// ---------------- kernel 4: prefilter + np-faithful re-rank + gather + loss ----------------
// One wave per row. Pool = 6 (2 splits x top-3) sorted by (value,idx); exact
// fp64 dots on 6, numpy-fp32-faithful distance ranking, fused gather+partials.
__global__ void refine_fused_kernel(const float* __restrict__ z, const float* __restrict__ e,
                                    const float* __restrict__ e2np,
                                    const float* __restrict__ cand_v,
                                    const u16* __restrict__ cand_i,
                                    int* __restrict__ counts, float* __restrict__ partials,
                                    float* __restrict__ out_zq, float* __restrict__ out_idx,
                                    int N) {
    __shared__ float buf[4][DDIM];
    __shared__ float ch[4][16];
    __shared__ float wsum[4];
    const int w = threadIdx.x >> 6;
    const int t = threadIdx.x & 63;
    const int n = blockIdx.x * 4 + w;

    float4 zv = *(const float4*)&z[(size_t)n * DDIM + t * 4];
    *(float4*)&buf[w][t * 4] = zv;
    __syncthreads();
    if (t < 16) ch[w][t] = np_sq_chain(buf[w], t);
    __syncthreads();

    // ---- pool: 6 candidates, (value,idx)-sorted insertion ----
    float bv[6]; int bi[6];
    #pragma unroll
    for (int c = 0; c < 6; ++c) { bv[c] = 3.4e38f; bi[c] = 0x7fffffff; }
    #pragma unroll
    for (int c = 0; c < 6; ++c) {
        int sp = c / 3, j = c - sp * 3;
        size_t off = ((size_t)sp * N + n) * 3 + j;
        float v  = cand_v[off];
        int   id = (int)cand_i[off];
        #pragma unroll
        for (int x = 0; x < 6; ++x) {
            if (v < bv[x] || (v == bv[x] && id < bi[x])) {
                for (int d = 5; d > x; --d) { bv[d] = bv[d - 1]; bi[d] = bi[d - 1]; }
                bv[x] = v; bi[x] = id;
                break;
            }
        }
    }

    float dotf[6];
    #pragma unroll
    for (int c = 0; c < 6; ++c) {
        int k = bi[c];
        float4 ev = *(const float4*)&e[(size_t)k * DDIM + t * 4];
        double p = (double)zv.x * (double)ev.x + (double)zv.y * (double)ev.y
                 + (double)zv.z * (double)ev.z + (double)zv.w * (double)ev.w;
        #pragma unroll
        for (int o = 32; o > 0; o >>= 1) p += __shfl_down(p, o);
        dotf[c] = (float)p;   // correctly-rounded fp32 of exact dot
    }

    int bk = 0;
    if (t == 0) {
        #pragma clang fp contract(off)
        float sx = np_combine16(ch[w]);
        float bd = 3.4e38f;
        bk = 0x7fffffff;
        #pragma unroll
        for (int c = 0; c < 6; ++c) {
            float twod = 2.0f * dotf[c];
            float t1 = sx - twod;
            float d2v = t1 + e2np[bi[c]];
            d2v = fmaxf(d2v, 0.0f);
            float d = sqrtf(d2v);
            if (d < bd || (d == bd && bi[c] < bk)) { bd = d; bk = bi[c]; }
        }
    }
    int wk = __shfl(bk, 0);

    float4 ev = *(const float4*)&e[(size_t)wk * DDIM + t * 4];
    *(float4*)&out_zq[(size_t)n * DDIM + t * 4] = ev;
    float dx = zv.x - ev.x, dy = zv.y - ev.y, dz = zv.z - ev.z, dw = zv.w - ev.w;
    float sq = dx * dx + dy * dy + dz * dz + dw * dw;
    #pragma unroll
    for (int o = 32; o > 0; o >>= 1) sq += __shfl_down(sq, o);
    if (t == 0) {
        wsum[w] = sq;
        atomicAdd(&counts[wk], 1);
        out_idx[n] = (float)wk;
    }
    __syncthreads();
    if (threadIdx.x == 0)
        partials[blockIdx.x] = wsum[0] + wsum[1] + wsum[2] + wsum[3];
}

// ---------------- kernel 5: finalize loss ----------------
__global__ void finalize_kernel(const int* __restrict__ counts, const float* __restrict__ partials,
                                float* __restrict__ out_loss, int K, int NB,
                                float invN, float invND) {
    int t = threadIdx.x;
    double ent = 0.0, sq = 0.0;
    for (int k = t; k < K; k += 256) {
        float p = (float)counts[k] * invN;
        ent += (double)(p * logf(p + 1e-10f));
    }
    for (int i = t; i < NB; i += 256) sq += (double)partials[i];
    #pragma unroll
    for (int o = 32; o > 0; o >>= 1) {
        ent += __shfl_down(ent, o);
        sq  += __shfl_down(sq, o);
    }
    __shared__ double e4[4], s4[4];
    if ((t & 63) == 0) { e4[t >> 6] = ent; s4[t >> 6] = sq; }
    __syncthreads();
    if (t == 0) {
        double esum = e4[0] + e4[1] + e4[2] + e4[3];
        double ssum = s4[0] + s4[1] + s4[2] + s4[3];
        float perp = expf((float)(-esum));
        float mean = (float)ssum * invND;
        out_loss[0] = 1.25f * mean - 0.01f * perp;
    }
}

extern "C" void kernel_launch(void* const* d_in, const int* in_sizes, int n_in,
                              void* d_out, int out_size, void* d_ws, size_t ws_size,
                              hipStream_t stream) {
    const float* z = (const float*)d_in[0];
    const float* e = (const float*)d_in[1];
    const int N = in_sizes[0] / DDIM;   // 32768
    const int K = in_sizes[1] / DDIM;   // 2048

    float* out      = (float*)d_out;
    float* out_zq   = out;
    float* out_loss = out + (size_t)N * DDIM;
    float* out_idx  = out_loss + 1;

    // ws layout (bytes):
    //   counts[K]            @ 0        (8 KB)
    //   e2np[K]              @ 8192     (8 KB)
    //   partials[N/4]        @ 16384    (32 KB)
    //   cand_v[2][N][3] f32  @ 49152    (768 KB)
    //   cand_i[2][N][3] u16  @ 835584   (384 KB)
    //   ebf_p (1 MB panels)  @ 1228800  -> total ~2.2 MB
    int*   counts   = (int*)d_ws;
    float* e2np     = (float*)((char*)d_ws + 8192);
    float* partials = (float*)((char*)d_ws + 16384);
    float* cand_v   = (float*)((char*)d_ws + 49152);
    u16*   cand_i   = (u16*)((char*)d_ws + 835584);
    char*  ebf_p    = (char*)d_ws + 1228800;

    code_norms_np_kernel<<<K, 64, 0, stream>>>(e, e2np, counts);
    convert_permute_e_kernel<<<K * 32 / 256, 256, 0, stream>>>(e, ebf_p);
    vq_cand_kernel<<<dim3(N / ROWS_PER_BLOCK, NSPLIT), 512, 0, stream>>>(z, ebf_p, e2np,
                                                                         cand_v, cand_i, N);
    refine_fused_kernel<<<N / 4, 256, 0, stream>>>(z, e, e2np, cand_v, cand_i,
                                                   counts, partials, out_zq, out_idx, N);
    finalize_kernel<<<1, 256, 0, stream>>>(counts, partials, out_loss, K, N / 4,
                                           1.0f / (float)N, 1.0f / (float)(N * DDIM));
}